// Round 4
// baseline (371.976 us; speedup 1.0000x reference)
//
#include <hip/hip_runtime.h>

using bf16x8 = __attribute__((ext_vector_type(8))) short;
using f32x4  = __attribute__((ext_vector_type(4))) float;

__device__ __forceinline__ unsigned short f2bf(float f) {
  unsigned u = __builtin_bit_cast(unsigned, f);
  u += 0x7fffu + ((u >> 16) & 1u);
  return (unsigned short)(u >> 16);
}

// ---------------- prep: fold weights once per launch ----------------
// ws layout (bytes):
//   [0      .. 32768)  MB  bf16 [128][128]: MB[c'][c] = M[c][c'],  M = Wq·Wk^T
//   [32768  .. 65536)  W2B bf16 [128][128]: W2B[c'][c] = W2[c][c'], W2 = Wv·Wp
//   [65536  .. 66048)  v2  f32 [128]: v2 = Wk·bq
//   [66048  .. 66560)  b2  f32 [128]: b2 = bv·Wp + bp
// Softmax-cancelled terms ((x·Wq·bk)1^T, bq·bk, P·1·(bv·Wp) absorbed) are exact.
__global__ __launch_bounds__(128) void prep_weights(
    const float* __restrict__ wqkv, const float* __restrict__ bqkv,
    const float* __restrict__ wproj, const float* __restrict__ bproj,
    void* __restrict__ ws) {
  __shared__ float W[128][129];
  unsigned short* wsu = (unsigned short*)ws;
  float* wsF = (float*)ws;
  const int tid = threadIdx.x;
  const int cp = blockIdx.x & 127;
  const bool second = blockIdx.x >= 128;     // second half computes W2B
  const int off = second ? 256 : 0;          // Wq cols 0..127 / Wv cols 256..383
  for (int r = 0; r < 128; ++r)
    W[r][tid] = wqkv[r * 384 + off + tid];   // coalesced row stage
  __syncthreads();
  float acc = 0.f;
  #pragma unroll 8
  for (int o = 0; o < 128; ++o) {
    float bc = second ? wproj[o * 128 + cp] : wqkv[cp * 384 + 128 + o];
    acc += W[tid][o] * bc;                   // stride 129 -> conflict-free
  }
  wsu[(second ? 16384 : 0) + cp * 128 + tid] = f2bf(acc);
  if (tid == 0) {
    float a2 = 0.f;
    if (!second) {
      for (int o = 0; o < 128; ++o) a2 += wqkv[cp * 384 + 128 + o] * bqkv[o];
      wsF[16384 + cp] = a2;                  // v2
    } else {
      for (int o = 0; o < 128; ++o) a2 += bqkv[256 + o] * wproj[o * 128 + cp];
      wsF[16512 + cp] = a2 + bproj[cp];      // b2
    }
  }
}

// ---------------- main: one block (4 waves) per window ----------------
// LDS = exactly 32 KiB -> up to 5 blocks/CU (VGPR cap 128 -> 4). XOR swizzle:
// short-index = r*128 + (c ^ ((r&7)<<3)).
// Overlays (row-ownership matches wave ownership -> only 3 barriers):
//   sX row r: [0..64) x cols 0..63 -> Z^T rows 64..127 ; [64..128) x cols 64..127 -> u-row (row 0)
//   sT row r: [0..64) T cols 0..63 -> P row r          ; [64..128) T cols 64..127 -> Z^T row r (r<64)
__global__ __launch_bounds__(256, 4) void win_attn(
    const float* __restrict__ x, const void* __restrict__ ws,
    float* __restrict__ out) {
  __shared__ unsigned short sX[8192];
  __shared__ unsigned short sT[8192];
  const unsigned short* MB  = (const unsigned short*)ws;
  const unsigned short* W2B = MB + 16384;
  const float* v2 = (const float*)((const char*)ws + 65536);
  const float* b2 = v2 + 128;

  const int tid  = threadIdx.x;
  const int wave = tid >> 6;
  const int lane = tid & 63;
  const int g    = lane >> 4;
  const int lr   = lane & 15;
  const float* xb = x + (size_t)blockIdx.x * 8192;
  const float scale = 0.08838834764831845f;   // 1/sqrt(128)
  const float l2e   = 1.4426950408889634f;

  // ---- S0: x (64x128 f32) -> sX bf16, swizzled ----
  #pragma unroll
  for (int i = 0; i < 8; ++i) {
    int e = tid + 256 * i;
    float4 v = ((const float4*)xb)[e];
    int r = e >> 5, c4 = (e & 31) * 4;
    ushort4 pk = make_ushort4(f2bf(v.x), f2bf(v.y), f2bf(v.z), f2bf(v.w));
    *(ushort4*)&sX[r * 128 + (c4 ^ ((r & 7) << 3))] = pk;
  }
  __syncthreads();   // B1

  // ---- w-dot (wave-local): w[16w+lr] = x_row · v2 ; u = exp(w*scale) ----
  float wacc = 0.f;
  {
    const int r = 16 * wave + lr;
    #pragma unroll
    for (int ii = 0; ii < 4; ++ii) {
      int c0 = 32 * g + 8 * ii;
      bf16x8 f = *(const bf16x8*)&sX[r * 128 + (c0 ^ ((r & 7) << 3))];
      #pragma unroll
      for (int e2 = 0; e2 < 8; ++e2) {
        float xf = __builtin_bit_cast(float, ((unsigned)(unsigned short)f[e2]) << 16);
        wacc += xf * v2[c0 + e2];
      }
    }
    wacc += __shfl_xor(wacc, 16, 64);
    wacc += __shfl_xor(wacc, 32, 64);
  }
  const float uu = exp2f(wacc * (scale * l2e));   // u[16w+lr], same across g

  // ---- S1: T = x·M (rows 16w..16w+16), write to sT ----
  f32x4 accT[8];
  #pragma unroll
  for (int ct = 0; ct < 8; ++ct) accT[ct] = f32x4{0.f,0.f,0.f,0.f};
  {
    const int ra = 16 * wave + lr;
    #pragma unroll
    for (int k0 = 0; k0 < 128; k0 += 32) {
      bf16x8 a = *(const bf16x8*)&sX[ra * 128 + ((k0 + 8 * g) ^ ((ra & 7) << 3))];
      #pragma unroll
      for (int ct = 0; ct < 8; ++ct) {
        bf16x8 bv = *(const bf16x8*)&MB[(16 * ct + lr) * 128 + k0 + 8 * g];
        accT[ct] = __builtin_amdgcn_mfma_f32_16x16x32_bf16(a, bv, accT[ct], 0, 0, 0);
      }
    }
  }
  #pragma unroll
  for (int ct = 0; ct < 8; ++ct)
    #pragma unroll
    for (int j = 0; j < 4; ++j) {
      int r = 16 * wave + 4 * g + j, c = 16 * ct + lr;
      sT[r * 128 + (c ^ ((r & 7) << 3))] = f2bf(accT[ct][j]);
    }
  // no barrier: T rows are wave-private; x stable since B1 (lgkmcnt ordering within wave)

  // ---- S2: S = T·x^T (rows 16w..), softmax (no sum reduce), P -> sT[0..64) ----
  f32x4 s[4];
  #pragma unroll
  for (int ct = 0; ct < 4; ++ct) s[ct] = f32x4{0.f,0.f,0.f,0.f};
  {
    const int ra = 16 * wave + lr;
    #pragma unroll
    for (int k0 = 0; k0 < 128; k0 += 32) {
      bf16x8 a = *(const bf16x8*)&sT[ra * 128 + ((k0 + 8 * g) ^ ((ra & 7) << 3))];
      #pragma unroll
      for (int ct = 0; ct < 4; ++ct) {
        int rb = 16 * ct + lr;
        bf16x8 bv = *(const bf16x8*)&sX[rb * 128 + ((k0 + 8 * g) ^ ((rb & 7) << 3))];
        s[ct] = __builtin_amdgcn_mfma_f32_16x16x32_bf16(a, bv, s[ct], 0, 0, 0);
      }
    }
  }
  #pragma unroll
  for (int j = 0; j < 4; ++j) {
    float mm = fmaxf(fmaxf(s[0][j], s[1][j]), fmaxf(s[2][j], s[3][j]));
    #pragma unroll
    for (int off = 1; off < 16; off <<= 1) mm = fmaxf(mm, __shfl_xor(mm, off, 64));
    const int r = 16 * wave + 4 * g + j;
    #pragma unroll
    for (int ct = 0; ct < 4; ++ct) {
      float p = exp2f((s[ct][j] - mm) * (scale * l2e));
      sT[r * 128 + ((16 * ct + lr) ^ ((r & 7) << 3))] = f2bf(p);
    }
  }

  // ---- S3: Z = x·W2 (rows 16w..) ----
  f32x4 z[8];
  #pragma unroll
  for (int ct = 0; ct < 8; ++ct) z[ct] = f32x4{0.f,0.f,0.f,0.f};
  {
    const int ra = 16 * wave + lr;
    #pragma unroll
    for (int k0 = 0; k0 < 128; k0 += 32) {
      bf16x8 a = *(const bf16x8*)&sX[ra * 128 + ((k0 + 8 * g) ^ ((ra & 7) << 3))];
      #pragma unroll
      for (int ct = 0; ct < 8; ++ct) {
        bf16x8 bv = *(const bf16x8*)&W2B[(16 * ct + lr) * 128 + k0 + 8 * g];
        z[ct] = __builtin_amdgcn_mfma_f32_16x16x32_bf16(a, bv, z[ct], 0, 0, 0);
      }
    }
  }
  __syncthreads();   // B2: all x-reads and all T-reads drained before overlays

  // write Z'^T = (diag(u)·Z)^T and the u-row
  {
    const int m0 = 16 * wave + 4 * g;
    float u4[4];
    #pragma unroll
    for (int j = 0; j < 4; ++j) u4[j] = __shfl(uu, 4 * g + j, 64);
    #pragma unroll
    for (int ct = 0; ct < 8; ++ct) {
      const int c = 16 * ct + lr;
      ushort4 pk = make_ushort4(f2bf(z[ct][0] * u4[0]), f2bf(z[ct][1] * u4[1]),
                                f2bf(z[ct][2] * u4[2]), f2bf(z[ct][3] * u4[3]));
      if (ct < 4) *(ushort4*)&sT[c * 128 + 64 + (m0 ^ ((c & 7) << 3))] = pk;
      else        *(ushort4*)&sX[(c - 64) * 128 + (m0 ^ ((c & 7) << 3))] = pk;
    }
    if (g == 0) sX[64 + 16 * wave + lr] = f2bf(uu);   // u-row, linear (swz key 0)
  }
  __syncthreads();   // B3

  // ---- S4: y = P·Z' ; rowsum via broadcast-u ones-column tile ----
  f32x4 y[8], y8;
  #pragma unroll
  for (int ct = 0; ct < 8; ++ct) y[ct] = f32x4{0.f,0.f,0.f,0.f};
  y8 = f32x4{0.f,0.f,0.f,0.f};
  {
    const int ra = 16 * wave + lr;
    #pragma unroll
    for (int k0 = 0; k0 < 64; k0 += 32) {
      const int mk = k0 + 8 * g;
      bf16x8 a = *(const bf16x8*)&sT[ra * 128 + (mk ^ ((ra & 7) << 3))];
      #pragma unroll
      for (int ct = 0; ct < 8; ++ct) {
        const int c = 16 * ct + lr;
        bf16x8 bv = (ct < 4)
          ? *(const bf16x8*)&sT[c * 128 + 64 + (mk ^ ((c & 7) << 3))]
          : *(const bf16x8*)&sX[(c - 64) * 128 + (mk ^ ((c & 7) << 3))];
        y[ct] = __builtin_amdgcn_mfma_f32_16x16x32_bf16(a, bv, y[ct], 0, 0, 0);
      }
      bf16x8 uv = *(const bf16x8*)&sX[64 + mk];   // broadcast: every col of this tile = rowsum
      y8 = __builtin_amdgcn_mfma_f32_16x16x32_bf16(a, uv, y8, 0, 0, 0);
    }
  }
  float* ob = out + (size_t)blockIdx.x * 8192;
  float rs4[4];
  #pragma unroll
  for (int j = 0; j < 4; ++j) rs4[j] = 1.0f / y8[j];
  #pragma unroll
  for (int ct = 0; ct < 8; ++ct) {
    const int c = 16 * ct + lr;
    const float bb = b2[c];
    #pragma unroll
    for (int j = 0; j < 4; ++j) {
      int r = 16 * wave + 4 * g + j;
      ob[r * 128 + c] = y[ct][j] * rs4[j] + bb;
    }
  }
}

extern "C" void kernel_launch(void* const* d_in, const int* in_sizes, int n_in,
                              void* d_out, int out_size, void* d_ws, size_t ws_size,
                              hipStream_t stream) {
  const float* x     = (const float*)d_in[0];
  const float* wqkv  = (const float*)d_in[1];
  const float* bqkv  = (const float*)d_in[2];
  const float* wproj = (const float*)d_in[3];
  const float* bproj = (const float*)d_in[4];
  float* out = (float*)d_out;

  prep_weights<<<256, 128, 0, stream>>>(wqkv, bqkv, wproj, bproj, d_ws);
  win_attn<<<4096, 256, 0, stream>>>(x, d_ws, out);
}